// Round 2
// baseline (417.445 us; speedup 1.0000x reference)
//
#include <hip/hip_runtime.h>

#define B_DIM 1024
#define C_DIM 256
#define ELL   9
#define E_DIM 10
#define K1    1
#define K2    4
#define K3    20

#define N_CUBIC 165            // C(9+2,3) monomials a<=b<=c
#define N_QUAD  45             // pairs a<=b
#define ROW3    80             // [l0 k0..19][v0 k0..19][v1][v2]
#define ROW2    16             // [l0 k0..3][v0][v1][v2]
#define ROW1    4              // [l0][v0][v1][v2]
#define T3_OFF  0
#define T2_OFF  (N_CUBIC * ROW3)            // 13200
#define T1_OFF  (T2_OFF + N_QUAD * ROW2)    // 13920
#define TBL_TOTAL (T1_OFF + ELL * ROW1)     // 13956 floats

// ---------------------------------------------------------------------------
// Kernel A: build symmetrized product-basis tables into d_ws. (validated r1)
// ---------------------------------------------------------------------------
__global__ void build_tables(const float* __restrict__ U1_l0,
                             const float* __restrict__ U2_l0,
                             const float* __restrict__ U3_l0,
                             const float* __restrict__ U1_l1,
                             const float* __restrict__ U2_l1,
                             const float* __restrict__ U3_l1,
                             float* __restrict__ tbl)
{
    int idx = blockIdx.x * blockDim.x + threadIdx.x;
    if (idx >= TBL_TOTAL) return;

    if (idx < T2_OFF) {
        int m = idx / ROW3, j = idx % ROW3;
        int a = 0, b = 0, c = 0, cnt = 0;
        for (int ai = 0; ai < ELL; ++ai)
            for (int bi = ai; bi < ELL; ++bi)
                for (int ci = bi; ci < ELL; ++ci) {
                    if (cnt == m) { a = ai; b = bi; c = ci; }
                    ++cnt;
                }
        int P[6][3] = {{a,b,c},{a,c,b},{b,a,c},{b,c,a},{c,a,b},{c,b,a}};
        float s = 0.f;
        for (int t = 0; t < 6; ++t) {
            bool dup = false;
            for (int u = 0; u < t; ++u)
                if (P[u][0]==P[t][0] && P[u][1]==P[t][1] && P[u][2]==P[t][2]) { dup = true; break; }
            if (dup) continue;
            int p0 = P[t][0], p1 = P[t][1], p2 = P[t][2];
            if (j < K3) {
                s += U3_l0[((p0*ELL + p1)*ELL + p2)*K3 + j];
            } else {
                int j2 = j - K3; int w = j2 / K3; int k = j2 % K3;
                s += U3_l1[(((w*ELL + p0)*ELL + p1)*ELL + p2)*K3 + k];
            }
        }
        tbl[idx] = s;
    } else if (idx < T1_OFF) {
        int r = idx - T2_OFF;
        int p = r / ROW2, j = r % ROW2;
        int a = 0, b = 0, cnt = 0;
        for (int ai = 0; ai < ELL; ++ai)
            for (int bi = ai; bi < ELL; ++bi) {
                if (cnt == p) { a = ai; b = bi; }
                ++cnt;
            }
        float s = 0.f;
        for (int t = 0; t < 2; ++t) {
            if (t == 1 && a == b) break;
            int p0 = (t == 0) ? a : b;
            int p1 = (t == 0) ? b : a;
            if (j < K2) {
                s += U2_l0[(p0*ELL + p1)*K2 + j];
            } else {
                int j2 = j - K2; int w = j2 / K2; int k = j2 % K2;
                s += U2_l1[((w*ELL + p0)*ELL + p1)*K2 + k];
            }
        }
        tbl[idx] = s;
    } else {
        int r = idx - T1_OFF;
        int i = r / ROW1, j = r % ROW1;
        float s;
        if (j == 0) s = U1_l0[i];
        else        s = U1_l1[(j - 1)*ELL + i];
        tbl[idx] = s;
    }
}

// ---------------------------------------------------------------------------
// Kernel B v2: one block per b (1024 threads). Thread = (q, c):
//   q = tid>>8 selects the output {0: out0, 1..3: out1 v=q-1}.
// All monomial loops FULLY UNROLLED (compile-time table offsets -> batched
// s_loads; x in registers with constant indices). l1 weighted-weights
// w~_l1[k][c] staged ONCE per block in LDS (v0/v1/v2 share them), so total
// weight traffic stays at ~0.5 MB/block instead of 3x that.
// ---------------------------------------------------------------------------
#define WT_K (K3 + K2 + K1)     // 25 staged l1 channels

__global__ __launch_bounds__(1024) void symcon_main(
    const float* __restrict__ x,  const float* __restrict__ y,
    const float* __restrict__ w1_l0, const float* __restrict__ w2_l0, const float* __restrict__ w3_l0,
    const float* __restrict__ w1_l1, const float* __restrict__ w2_l1, const float* __restrict__ w3_l1,
    const float* __restrict__ tbl, float* __restrict__ out)
{
    const int b   = blockIdx.x;
    const int tid = threadIdx.x;
    const int q   = tid >> 8;        // wave-uniform (4 waves per q-group)
    const int c   = tid & 255;

    __shared__ float wt_l1[WT_K][C_DIM];   // 25.6 KB

    // ---- stage w~_l1[k][c] = sum_e y[b,e] * w_l1[e,k,c] ----
    {
        for (int t = tid; t < WT_K * C_DIM; t += 1024) {
            int k  = t >> 8;
            int cc = t & 255;
            float s = 0.f;
            if (k < K3) {
                #pragma unroll
                for (int e = 0; e < E_DIM; ++e)
                    s = fmaf(y[b*E_DIM + e], w3_l1[(e*K3 + k)*C_DIM + cc], s);
            } else if (k < K3 + K2) {
                int kk = k - K3;
                #pragma unroll
                for (int e = 0; e < E_DIM; ++e)
                    s = fmaf(y[b*E_DIM + e], w2_l1[(e*K2 + kk)*C_DIM + cc], s);
            } else {
                #pragma unroll
                for (int e = 0; e < E_DIM; ++e)
                    s = fmaf(y[b*E_DIM + e], w1_l1[e*C_DIM + cc], s);
            }
            wt_l1[k][cc] = s;
        }
    }
    __syncthreads();

    // ---- x into registers (constant indices after unroll) ----
    float xv[ELL];
    {
        const float* xp = x + (size_t)(b*C_DIM + c)*ELL;
        #pragma unroll
        for (int i = 0; i < ELL; ++i) xv[i] = xp[i];
    }

    float acc3[K3];
    #pragma unroll
    for (int j = 0; j < K3; ++j) acc3[j] = 0.f;
    float acc2[K2];
    #pragma unroll
    for (int j = 0; j < K2; ++j) acc2[j] = 0.f;
    float acc1 = 0.f;

    const float* tq3 = tbl + T3_OFF + q*K3;   // this q's 20-channel slice
    const float* tq2 = tbl + T2_OFF + q*K2;
    const float* tq1 = tbl + T1_OFF + q*K1;

    // ---- cubic: 165 monomials, fully unrolled ----
    {
        int m = 0;
        #pragma unroll
        for (int a = 0; a < ELL; ++a) {
            #pragma unroll
            for (int b2 = a; b2 < ELL; ++b2) {
                float xab = xv[a] * xv[b2];
                #pragma unroll
                for (int c2 = b2; c2 < ELL; ++c2) {
                    float x3 = xab * xv[c2];
                    #pragma unroll
                    for (int j = 0; j < K3; ++j)
                        acc3[j] = fmaf(tq3[m*ROW3 + j], x3, acc3[j]);
                    ++m;
                }
            }
        }
    }
    // ---- quadratic: 45 monomials ----
    {
        int m = 0;
        #pragma unroll
        for (int a = 0; a < ELL; ++a) {
            #pragma unroll
            for (int b2 = a; b2 < ELL; ++b2) {
                float x2 = xv[a] * xv[b2];
                #pragma unroll
                for (int j = 0; j < K2; ++j)
                    acc2[j] = fmaf(tq2[m*ROW2 + j], x2, acc2[j]);
                ++m;
            }
        }
    }
    // ---- linear ----
    {
        #pragma unroll
        for (int i = 0; i < ELL; ++i)
            acc1 = fmaf(tq1[i*ROW1], xv[i], acc1);
    }

    // ---- combine ----
    if (q == 0) {
        float yb[E_DIM];
        #pragma unroll
        for (int e = 0; e < E_DIM; ++e) yb[e] = y[b*E_DIM + e];

        float o = 0.f;
        #pragma unroll
        for (int k = 0; k < K3; ++k) {
            float wt = 0.f;
            #pragma unroll
            for (int e = 0; e < E_DIM; ++e)
                wt = fmaf(yb[e], w3_l0[(e*K3 + k)*C_DIM + c], wt);
            o = fmaf(wt, acc3[k], o);
        }
        #pragma unroll
        for (int k = 0; k < K2; ++k) {
            float wt = 0.f;
            #pragma unroll
            for (int e = 0; e < E_DIM; ++e)
                wt = fmaf(yb[e], w2_l0[(e*K2 + k)*C_DIM + c], wt);
            o = fmaf(wt, acc2[k], o);
        }
        {
            float wt = 0.f;
            #pragma unroll
            for (int e = 0; e < E_DIM; ++e)
                wt = fmaf(yb[e], w1_l0[e*C_DIM + c], wt);
            o = fmaf(wt, acc1, o);
        }
        out[b*C_DIM + c] = o;
    } else {
        float o = 0.f;
        #pragma unroll
        for (int k = 0; k < K3; ++k)
            o = fmaf(wt_l1[k][c], acc3[k], o);
        #pragma unroll
        for (int k = 0; k < K2; ++k)
            o = fmaf(wt_l1[K3 + k][c], acc2[k], o);
        o = fmaf(wt_l1[K3 + K2][c], acc1, o);

        out[B_DIM*C_DIM + (size_t)(b*C_DIM + c)*3 + (q - 1)] = o;
    }
}

// ---------------------------------------------------------------------------
extern "C" void kernel_launch(void* const* d_in, const int* in_sizes, int n_in,
                              void* d_out, int out_size, void* d_ws, size_t ws_size,
                              hipStream_t stream)
{
    const float* x     = (const float*)d_in[0];
    const float* y     = (const float*)d_in[1];
    const float* U1_l0 = (const float*)d_in[2];
    const float* U2_l0 = (const float*)d_in[3];
    const float* U3_l0 = (const float*)d_in[4];
    const float* U1_l1 = (const float*)d_in[5];
    const float* U2_l1 = (const float*)d_in[6];
    const float* U3_l1 = (const float*)d_in[7];
    const float* w1_l0 = (const float*)d_in[8];
    const float* w2_l0 = (const float*)d_in[9];
    const float* w3_l0 = (const float*)d_in[10];
    const float* w1_l1 = (const float*)d_in[11];
    const float* w2_l1 = (const float*)d_in[12];
    const float* w3_l1 = (const float*)d_in[13];

    float* tbl  = (float*)d_ws;
    float* outp = (float*)d_out;

    build_tables<<<(TBL_TOTAL + 255)/256, 256, 0, stream>>>(
        U1_l0, U2_l0, U3_l0, U1_l1, U2_l1, U3_l1, tbl);

    symcon_main<<<B_DIM, 1024, 0, stream>>>(
        x, y, w1_l0, w2_l0, w3_l0, w1_l1, w2_l1, w3_l1, tbl, outp);
}

// Round 3
// 157.727 us; speedup vs baseline: 2.6466x; 2.6466x over previous
//
#include <hip/hip_runtime.h>

#define B_DIM 1024
#define C_DIM 256
#define ELL   9
#define E_DIM 10
#define K1    1
#define K2    4
#define K3    20

#define N_CUBIC 165            // C(9+2,3) monomials a<=b<=c
#define N_QUAD  45             // pairs a<=b
#define ROW3    80             // [l0 k0..19][v0 k0..19][v1][v2]
#define ROW2    16             // [l0 k0..3][v0][v1][v2]
#define ROW1    4              // [l0][v0][v1][v2]
#define T3_OFF  0
#define T2_OFF  (N_CUBIC * ROW3)            // 13200
#define T1_OFF  (T2_OFF + N_QUAD * ROW2)    // 13920
#define TBL_TOTAL (T1_OFF + ELL * ROW1)     // 13956 floats

// ---------------------------------------------------------------------------
// Kernel A: build symmetrized product-basis tables into d_ws. (validated r1)
// ---------------------------------------------------------------------------
__global__ void build_tables(const float* __restrict__ U1_l0,
                             const float* __restrict__ U2_l0,
                             const float* __restrict__ U3_l0,
                             const float* __restrict__ U1_l1,
                             const float* __restrict__ U2_l1,
                             const float* __restrict__ U3_l1,
                             float* __restrict__ tbl)
{
    int idx = blockIdx.x * blockDim.x + threadIdx.x;
    if (idx >= TBL_TOTAL) return;

    if (idx < T2_OFF) {
        int m = idx / ROW3, j = idx % ROW3;
        int a = 0, b = 0, c = 0, cnt = 0;
        for (int ai = 0; ai < ELL; ++ai)
            for (int bi = ai; bi < ELL; ++bi)
                for (int ci = bi; ci < ELL; ++ci) {
                    if (cnt == m) { a = ai; b = bi; c = ci; }
                    ++cnt;
                }
        int P[6][3] = {{a,b,c},{a,c,b},{b,a,c},{b,c,a},{c,a,b},{c,b,a}};
        float s = 0.f;
        for (int t = 0; t < 6; ++t) {
            bool dup = false;
            for (int u = 0; u < t; ++u)
                if (P[u][0]==P[t][0] && P[u][1]==P[t][1] && P[u][2]==P[t][2]) { dup = true; break; }
            if (dup) continue;
            int p0 = P[t][0], p1 = P[t][1], p2 = P[t][2];
            if (j < K3) {
                s += U3_l0[((p0*ELL + p1)*ELL + p2)*K3 + j];
            } else {
                int j2 = j - K3; int w = j2 / K3; int k = j2 % K3;
                s += U3_l1[(((w*ELL + p0)*ELL + p1)*ELL + p2)*K3 + k];
            }
        }
        tbl[idx] = s;
    } else if (idx < T1_OFF) {
        int r = idx - T2_OFF;
        int p = r / ROW2, j = r % ROW2;
        int a = 0, b = 0, cnt = 0;
        for (int ai = 0; ai < ELL; ++ai)
            for (int bi = ai; bi < ELL; ++bi) {
                if (cnt == p) { a = ai; b = bi; }
                ++cnt;
            }
        float s = 0.f;
        for (int t = 0; t < 2; ++t) {
            if (t == 1 && a == b) break;
            int p0 = (t == 0) ? a : b;
            int p1 = (t == 0) ? b : a;
            if (j < K2) {
                s += U2_l0[(p0*ELL + p1)*K2 + j];
            } else {
                int j2 = j - K2; int w = j2 / K2; int k = j2 % K2;
                s += U2_l1[((w*ELL + p0)*ELL + p1)*K2 + k];
            }
        }
        tbl[idx] = s;
    } else {
        int r = idx - T1_OFF;
        int i = r / ROW1, j = r % ROW1;
        float s;
        if (j == 0) s = U1_l0[i];
        else        s = U1_l1[(j - 1)*ELL + i];
        tbl[idx] = s;
    }
}

// ---------------------------------------------------------------------------
// Kernel B v3: one block per b (1024 threads). Thread = (q, c):
//   q = readfirstlane(tid>>8) -> SGPR, so the table slice pointer is provably
//   wave-uniform and the fully-unrolled monomial loops compile to batched
//   s_load + v_fmac with SGPR operand (no vector loads in the hot loop).
// Both w~_l0 and w~_l1 are staged once per block into LDS (50x256 = 51 KB);
// the combine phase is pure LDS for every q-group.
// ---------------------------------------------------------------------------
#define WT_K (K3 + K2 + K1)     // 25 channels per parity

__global__ __launch_bounds__(1024) void symcon_main(
    const float* __restrict__ x,  const float* __restrict__ y,
    const float* __restrict__ w1_l0, const float* __restrict__ w2_l0, const float* __restrict__ w3_l0,
    const float* __restrict__ w1_l1, const float* __restrict__ w2_l1, const float* __restrict__ w3_l1,
    const float* __restrict__ tbl, float* __restrict__ out)
{
    const int b   = blockIdx.x;
    const int tid = threadIdx.x;
    const int q   = __builtin_amdgcn_readfirstlane(tid >> 8);  // SGPR: 0..3
    const int c   = tid & 255;

    // rows 0..24 = l1 (k3:0..19, k2:20..23, k1:24); rows 25..49 = l0 same order
    __shared__ float wt[2 * WT_K][C_DIM];   // 51.2 KB

    // ---- cooperative staging of weighted weights ----
    {
        float yb[E_DIM];
        #pragma unroll
        for (int e = 0; e < E_DIM; ++e) yb[e] = y[b*E_DIM + e];

        for (int t = tid; t < 2 * WT_K * C_DIM; t += 1024) {
            int k  = t >> 8;        // 0..49
            int cc = t & 255;
            int par = (k >= WT_K);  // 0 = l1, 1 = l0
            int kk  = par ? (k - WT_K) : k;
            float s = 0.f;
            if (kk < K3) {
                const float* wp = par ? w3_l0 : w3_l1;
                #pragma unroll
                for (int e = 0; e < E_DIM; ++e)
                    s = fmaf(yb[e], wp[(e*K3 + kk)*C_DIM + cc], s);
            } else if (kk < K3 + K2) {
                const float* wp = par ? w2_l0 : w2_l1;
                int k2 = kk - K3;
                #pragma unroll
                for (int e = 0; e < E_DIM; ++e)
                    s = fmaf(yb[e], wp[(e*K2 + k2)*C_DIM + cc], s);
            } else {
                const float* wp = par ? w1_l0 : w1_l1;
                #pragma unroll
                for (int e = 0; e < E_DIM; ++e)
                    s = fmaf(yb[e], wp[e*C_DIM + cc], s);
            }
            wt[k][cc] = s;
        }
    }
    __syncthreads();

    // ---- x into registers (constant indices after unroll) ----
    float xv[ELL];
    {
        const float* xp = x + (size_t)(b*C_DIM + c)*ELL;
        #pragma unroll
        for (int i = 0; i < ELL; ++i) xv[i] = xp[i];
    }

    float acc3[K3];
    #pragma unroll
    for (int j = 0; j < K3; ++j) acc3[j] = 0.f;
    float acc2[K2];
    #pragma unroll
    for (int j = 0; j < K2; ++j) acc2[j] = 0.f;
    float acc1 = 0.f;

    // scalar (wave-uniform) table slice pointers
    const float* tq3 = tbl + T3_OFF + q*K3;
    const float* tq2 = tbl + T2_OFF + q*K2;
    const float* tq1 = tbl + T1_OFF + q*K1;

    // ---- cubic: 165 monomials, fully unrolled -> batched s_loads ----
    {
        int m = 0;
        #pragma unroll
        for (int a = 0; a < ELL; ++a) {
            #pragma unroll
            for (int b2 = a; b2 < ELL; ++b2) {
                float xab = xv[a] * xv[b2];
                #pragma unroll
                for (int c2 = b2; c2 < ELL; ++c2) {
                    float x3 = xab * xv[c2];
                    #pragma unroll
                    for (int j = 0; j < K3; ++j)
                        acc3[j] = fmaf(tq3[m*ROW3 + j], x3, acc3[j]);
                    ++m;
                }
            }
        }
    }
    // ---- quadratic: 45 monomials ----
    {
        int m = 0;
        #pragma unroll
        for (int a = 0; a < ELL; ++a) {
            #pragma unroll
            for (int b2 = a; b2 < ELL; ++b2) {
                float x2 = xv[a] * xv[b2];
                #pragma unroll
                for (int j = 0; j < K2; ++j)
                    acc2[j] = fmaf(tq2[m*ROW2 + j], x2, acc2[j]);
                ++m;
            }
        }
    }
    // ---- linear ----
    {
        #pragma unroll
        for (int i = 0; i < ELL; ++i)
            acc1 = fmaf(tq1[i*ROW1], xv[i], acc1);
    }

    // ---- combine: pure LDS reads for every q-group ----
    const float* wrow = (q == 0) ? &wt[WT_K][0] : &wt[0][0];  // scalar select
    float o = 0.f;
    #pragma unroll
    for (int k = 0; k < K3; ++k)
        o = fmaf(wrow[k*C_DIM + c], acc3[k], o);
    #pragma unroll
    for (int k = 0; k < K2; ++k)
        o = fmaf(wrow[(K3 + k)*C_DIM + c], acc2[k], o);
    o = fmaf(wrow[(K3 + K2)*C_DIM + c], acc1, o);

    if (q == 0) {
        out[b*C_DIM + c] = o;
    } else {
        out[B_DIM*C_DIM + (size_t)(b*C_DIM + c)*3 + (q - 1)] = o;
    }
}

// ---------------------------------------------------------------------------
extern "C" void kernel_launch(void* const* d_in, const int* in_sizes, int n_in,
                              void* d_out, int out_size, void* d_ws, size_t ws_size,
                              hipStream_t stream)
{
    const float* x     = (const float*)d_in[0];
    const float* y     = (const float*)d_in[1];
    const float* U1_l0 = (const float*)d_in[2];
    const float* U2_l0 = (const float*)d_in[3];
    const float* U3_l0 = (const float*)d_in[4];
    const float* U1_l1 = (const float*)d_in[5];
    const float* U2_l1 = (const float*)d_in[6];
    const float* U3_l1 = (const float*)d_in[7];
    const float* w1_l0 = (const float*)d_in[8];
    const float* w2_l0 = (const float*)d_in[9];
    const float* w3_l0 = (const float*)d_in[10];
    const float* w1_l1 = (const float*)d_in[11];
    const float* w2_l1 = (const float*)d_in[12];
    const float* w3_l1 = (const float*)d_in[13];

    float* tbl  = (float*)d_ws;
    float* outp = (float*)d_out;

    build_tables<<<(TBL_TOTAL + 255)/256, 256, 0, stream>>>(
        U1_l0, U2_l0, U3_l0, U1_l1, U2_l1, U3_l1, tbl);

    symcon_main<<<B_DIM, 1024, 0, stream>>>(
        x, y, w1_l0, w2_l0, w3_l0, w1_l1, w2_l1, w3_l1, tbl, outp);
}